// Round 7
// baseline (920.996 us; speedup 1.0000x reference)
//
#include <hip/hip_runtime.h>
#include <hip/hip_bf16.h>

#define NN 50000    // nodes
#define NE 100000   // edges
#define NG 2048     // graphs
#define NF 14
#define D 64
#define EB 64       // edges per tile in msg kernel

typedef __attribute__((ext_vector_type(8))) short bf16x8;
typedef __attribute__((ext_vector_type(4))) float f32x4;
typedef unsigned int u32;

__device__ __forceinline__ float sigmoidf(float x) { return 1.f / (1.f + expf(-x)); }

// async 16B/lane global->LDS DMA (lds dest = wave-uniform base + lane*16)
__device__ __forceinline__ void async_copy16(void* lds, const void* g) {
    __builtin_amdgcn_global_load_lds(
        (const __attribute__((address_space(1))) u32*)g,
        (__attribute__((address_space(3))) u32*)lds, 16, 0, 0);
}

// ---------------- utility ----------------
// swizzled bf16 W2: w2s[i][o][chunk (c+o)&15] = w2[(i*64+o)*128 + c*8 .. +7]
__global__ void swz_w2_kernel(const float* __restrict__ w2, __hip_bfloat16* __restrict__ w2s) {
    int t = blockIdx.x * 256 + threadIdx.x;   // 65536 chunks
    int i = t >> 10, o = (t >> 4) & 63, c = t & 15;
    const float* src = w2 + ((size_t)(i * 64 + o)) * 128 + c * 8;
    union { __hip_bfloat16 b[8]; uint4 u; } pk;
#pragma unroll
    for (int j = 0; j < 8; j++) pk.b[j] = __float2bfloat16(src[j]);
    *(uint4*)((char*)w2s + (size_t)i * 16384 + o * 256 + ((c + o) & 15) * 16) = pk.u;
}

// dst[c*rows + r] = src[r*cols + c]
__global__ void transpose_kernel(const float* __restrict__ src, float* __restrict__ dst,
                                 int rows, int cols) {
    int idx = blockIdx.x * 256 + threadIdx.x;
    if (idx < rows * cols) {
        int r = idx / cols, c = idx - r * cols;
        dst[c * rows + r] = src[idx];
    }
}

// ---------------- lin0: out = relu(x @ lin0_w.T + b) ----------------
__global__ void lin0_kernel(const float* __restrict__ x, const float* __restrict__ w,
                            const float* __restrict__ b, float* __restrict__ out) {
    int grp = threadIdx.x >> 6;
    int d = threadIdx.x & 63;
    int n = blockIdx.x * 4 + grp;
    __shared__ float xs[4][NF];
    int t = threadIdx.x;
    if (t < 4 * NF) {
        int r = t / NF, c = t - r * NF;
        int nn2 = blockIdx.x * 4 + r;
        xs[r][c] = (nn2 < NN) ? x[nn2 * NF + c] : 0.f;
    }
    __syncthreads();
    if (n >= NN) return;
    float acc = b[d];
#pragma unroll
    for (int k = 0; k < NF; k++) acc += xs[grp][k] * w[d * NF + k];
    out[n * D + d] = fmaxf(acc, 0.f);
}

// ================= MFMA fused message kernel v3 =================
// 256 threads = 4 waves; wave = ct (o-cols ct*16..+15), rt=4 row-tiles (64 edges).
// W2 slices DMA'd via global_load_lds into unpadded swizzled Bs.
__global__ __launch_bounds__(256, 3) void msg_mfma_kernel(
    const float* __restrict__ h, const float* __restrict__ ea,
    const float* __restrict__ w1, const float* __restrict__ b1,
    const __hip_bfloat16* __restrict__ w2s,  // swizzled bf16 [64][64][16 chunks]
    const float* __restrict__ b2, const int* __restrict__ ei,
    float* __restrict__ agg)
{
    // pool: Bs[2][64][128] bf16 (32 KB). Aliases hid[64][136] (preamble) and B2s[64][72] (b2 pass).
    __shared__ __align__(16) char pool[32768];
    __hip_bfloat16 (*hid)[136] = (__hip_bfloat16(*)[136])pool;
    __hip_bfloat16 (*B2s)[72] = (__hip_bfloat16(*)[72])pool;
    __shared__ __align__(16) __hip_bfloat16 hsT[64][72];  // hsT[i][e] = bf16(h[src_e][i])
    __shared__ float w1s[128][4];
    __shared__ float b1s[128];
    __shared__ int didx[EB];

    int tid = threadIdx.x;
    int e0 = blockIdx.x * EB;

    // --- stage didx / w1s / b1s ---
    if (tid < EB) {
        didx[tid] = (e0 + tid < NE) ? ei[NE + e0 + tid] : -1;
    } else if (tid < EB + 128) {
        int k = tid - EB;
        w1s[k][0] = w1[k * 4 + 0]; w1s[k][1] = w1[k * 4 + 1];
        w1s[k][2] = w1[k * 4 + 2]; w1s[k][3] = w1[k * 4 + 3];
        b1s[k] = b1[k];
    }
    // --- gather h[src] -> hsT (bf16, [i][e]); 4 threads per edge ---
    {
        int e = tid >> 2, sg = (tid & 3) * 16;
        int ge = e0 + e;
        int src = (ge < NE) ? ei[ge] : 0;
        const float4* hp = (const float4*)(h + (size_t)src * 64 + sg);
#pragma unroll
        for (int u = 0; u < 4; u++) {
            float4 v = (ge < NE) ? hp[u] : make_float4(0.f, 0.f, 0.f, 0.f);
            hsT[sg + u * 4 + 0][e] = __float2bfloat16(v.x);
            hsT[sg + u * 4 + 1][e] = __float2bfloat16(v.y);
            hsT[sg + u * 4 + 2][e] = __float2bfloat16(v.z);
            hsT[sg + u * 4 + 3][e] = __float2bfloat16(v.w);
        }
    }
    __syncthreads();  // w1s/b1s ready
    // --- hid[e][k] = relu(b1[k] + ea[e]·w1[k]) bf16 ---
    {
        int e = tid & 63, kb = (tid >> 6) * 32;
        int ge = e0 + e;
        float4 av = (ge < NE) ? *(const float4*)(ea + (size_t)ge * 4)
                              : make_float4(0.f, 0.f, 0.f, 0.f);
        for (int k = kb; k < kb + 32; k += 4) {
            union { __hip_bfloat16 b[4]; uint2 uu; } pk;
#pragma unroll
            for (int u = 0; u < 4; u++) {
                float v = b1s[k + u] + av.x * w1s[k + u][0] + av.y * w1s[k + u][1] +
                          av.z * w1s[k + u][2] + av.w * w1s[k + u][3];
                pk.b[u] = __float2bfloat16((ge < NE) ? fmaxf(v, 0.f) : 0.f);
            }
            *(uint2*)&hid[e][k] = pk.uu;
        }
    }
    __syncthreads();  // hid ready

    int lane = tid & 63;
    int wid = tid >> 6;  // = ct
    int n = lane & 15, q = lane >> 4;
    int ocol = wid * 16 + n;

    // A-fragments (i-invariant): 4 row-tiles x 4 k-steps
    bf16x8 afr[4][4];
#pragma unroll
    for (int rt = 0; rt < 4; rt++)
#pragma unroll
        for (int ks = 0; ks < 4; ks++)
            afr[rt][ks] = *(const bf16x8*)&hid[rt * 16 + n][ks * 32 + q * 8];
    __syncthreads();  // hid dead; pool becomes Bs

    // per-lane swizzled B-frag offsets (i-invariant)
    int boff[4];
#pragma unroll
    for (int ks = 0; ks < 4; ks++)
        boff[ks] = ocol * 256 + (((ks * 4 + q) + ocol) & 15) * 16;

    // DMA stage of slice 0 into Bs[0]
    {
        const char* g = (const char*)w2s + (size_t)wid * 4096 + lane * 16;
        char* l = pool + wid * 4096;
#pragma unroll
        for (int j = 0; j < 4; j++) async_copy16(l + j * 1024, g + j * 1024);
    }
    __syncthreads();  // Bs[0] ready (compiler drains vmcnt before barrier)

    f32x4 acc[4];
#pragma unroll
    for (int rt = 0; rt < 4; rt++) acc[rt] = (f32x4){0.f, 0.f, 0.f, 0.f};

    for (int i = 0; i < 64; i++) {
        const int cur = i & 1;
        char* bbase = pool + cur * 16384;
        // async DMA of next slice into the other buffer
        if (i + 1 < 64) {
            const char* g = (const char*)w2s + (size_t)(i + 1) * 16384 + wid * 4096 + lane * 16;
            char* l = pool + (cur ^ 1) * 16384 + wid * 4096;
#pragma unroll
            for (int j = 0; j < 4; j++) async_copy16(l + j * 1024, g + j * 1024);
        }
        // MFMA: ks-outer, 4 independent accumulator chains
        f32x4 S[4];
#pragma unroll
        for (int rt = 0; rt < 4; rt++) S[rt] = (f32x4){0.f, 0.f, 0.f, 0.f};
#pragma unroll
        for (int ks = 0; ks < 4; ks++) {
            bf16x8 bfr = *(const bf16x8*)(bbase + boff[ks]);
#pragma unroll
            for (int rt = 0; rt < 4; rt++)
                S[rt] = __builtin_amdgcn_mfma_f32_16x16x32_bf16(afr[rt][ks], bfr, S[rt], 0, 0, 0);
        }
        // fixup: acc[rt] += h[src, i] * S[rt]  (bf16 pairs from hsT, b64 reads)
#pragma unroll
        for (int rt = 0; rt < 4; rt++) {
            uint2 hm = *(const uint2*)&hsT[i][rt * 16 + q * 4];
            float m0 = __uint_as_float(hm.x << 16);
            float m1 = __uint_as_float(hm.x & 0xffff0000u);
            float m2 = __uint_as_float(hm.y << 16);
            float m3 = __uint_as_float(hm.y & 0xffff0000u);
            acc[rt][0] += m0 * S[rt][0];
            acc[rt][1] += m1 * S[rt][1];
            acc[rt][2] += m2 * S[rt][2];
            acc[rt][3] += m3 * S[rt][3];
        }
        __syncthreads();
    }

    // ---- b2 pass: acc[e,o] += sum_i h[src_e,i] * b2[i*64+o] via MFMA ----
    for (int g2 = tid; g2 < 4096; g2 += 256) {
        B2s[g2 & 63][g2 >> 6] = __float2bfloat16(b2[g2]);
    }
    __syncthreads();
#pragma unroll
    for (int rt = 0; rt < 4; rt++) {
        f32x4 S2 = (f32x4){0.f, 0.f, 0.f, 0.f};
#pragma unroll
        for (int ks2 = 0; ks2 < 2; ks2++) {
            union { __hip_bfloat16 b[8]; bf16x8 v; } pk;
#pragma unroll
            for (int j = 0; j < 8; j++)
                pk.b[j] = hsT[ks2 * 32 + q * 8 + j][rt * 16 + n];
            bf16x8 bfr2 = *(const bf16x8*)&B2s[ocol][ks2 * 32 + q * 8];
            S2 = __builtin_amdgcn_mfma_f32_16x16x32_bf16(pk.v, bfr2, S2, 0, 0, 0);
        }
#pragma unroll
        for (int r = 0; r < 4; r++) acc[rt][r] += S2[r];
    }

    // scatter
#pragma unroll
    for (int rt = 0; rt < 4; rt++)
#pragma unroll
        for (int r = 0; r < 4; r++) {
            int e = rt * 16 + q * 4 + r;
            int dn = didx[e];
            if (dn >= 0) atomicAdd(&agg[(size_t)dn * 64 + ocol], acc[rt][r]);
        }
}

// ---------------- degree ----------------
__global__ void deg_kernel(const int* __restrict__ ei, float* __restrict__ deg) {
    int e = blockIdx.x * 256 + threadIdx.x;
    if (e < NE) atomicAdd(&deg[ei[NE + e]], 1.0f);
}
__global__ void invdeg_kernel(float* deg) {
    int n = blockIdx.x * 256 + threadIdx.x;
    if (n < NN) deg[n] = 1.0f / fmaxf(deg[n], 1.0f);
}

// ---------------- fused conv + GRU ----------------
__global__ __launch_bounds__(256) void conv_gru_kernel(
    float* __restrict__ h, const float* __restrict__ agg, const float* __restrict__ invdeg,
    const float* __restrict__ root, const float* __restrict__ cbias,
    const float* __restrict__ wihT, const float* __restrict__ whhT,
    const float* __restrict__ bih, const float* __restrict__ bhh)
{
    int tid = threadIdx.x;
    int grp = tid >> 6;
    int j = tid & 63;
    int n0 = blockIdx.x * 16;
    int nd0 = grp * 4;
    __shared__ float hs[16][64];
    __shared__ float ms[16][68];
    for (int i = tid; i < 1024; i += 256) {
        int nd = i >> 6, dd = i & 63;
        hs[nd][dd] = h[(n0 + nd) * D + dd];
    }
    __syncthreads();
    float mm[4] = {};
#pragma unroll 8
    for (int k = 0; k < 64; k++) {
        float rv = root[k * 64 + j];
#pragma unroll
        for (int q = 0; q < 4; q++) mm[q] += hs[nd0 + q][k] * rv;
    }
    float cb = cbias[j];
#pragma unroll
    for (int q = 0; q < 4; q++) {
        int nn2 = n0 + nd0 + q;
        float v = mm[q] + agg[(size_t)nn2 * 64 + j] * invdeg[nn2] + cb;
        ms[nd0 + q][j] = fmaxf(v, 0.f);
    }
    __syncthreads();
    float air[4] = {}, aiz[4] = {}, ain[4] = {};
    float ahr[4] = {}, ahz[4] = {}, ahn[4] = {};
#pragma unroll 4
    for (int k = 0; k < 64; k++) {
        float wr = wihT[k * 192 + j];
        float wz = wihT[k * 192 + 64 + j];
        float wn = wihT[k * 192 + 128 + j];
        float vr = whhT[k * 192 + j];
        float vz = whhT[k * 192 + 64 + j];
        float vn = whhT[k * 192 + 128 + j];
#pragma unroll
        for (int q = 0; q < 4; q++) {
            float mv = ms[nd0 + q][k], hv = hs[nd0 + q][k];
            air[q] = fmaf(mv, wr, air[q]);
            aiz[q] = fmaf(mv, wz, aiz[q]);
            ain[q] = fmaf(mv, wn, ain[q]);
            ahr[q] = fmaf(hv, vr, ahr[q]);
            ahz[q] = fmaf(hv, vz, ahz[q]);
            ahn[q] = fmaf(hv, vn, ahn[q]);
        }
    }
    float br = bih[j], bz = bih[64 + j], bn = bih[128 + j];
    float cr = bhh[j], cz = bhh[64 + j], cn = bhh[128 + j];
#pragma unroll
    for (int q = 0; q < 4; q++) {
        float r = sigmoidf(air[q] + br + ahr[q] + cr);
        float z = sigmoidf(aiz[q] + bz + ahz[q] + cz);
        float nn2 = tanhf(ain[q] + bn + r * (ahn[q] + cn));
        float hv = hs[nd0 + q][j];
        h[(n0 + nd0 + q) * D + j] = (1.f - z) * nn2 + z * hv;
    }
}

// ---------------- graph starts (batch sorted) ----------------
__global__ void starts_kernel(const int* __restrict__ batch, int* __restrict__ start) {
    int n = blockIdx.x * 256 + threadIdx.x;
    if (n >= NN) return;
    int b = batch[n];
    int bp = (n == 0) ? -1 : batch[n - 1];
    for (int g = bp + 1; g <= b; g++) start[g] = n;
    if (n == NN - 1) {
        for (int g = b + 1; g <= NG; g++) start[g] = NN;
    }
}

// ---------------- Set2Set LSTM step ----------------
__global__ void s2s_lstm_kernel(const float* __restrict__ qstar, float* __restrict__ hh,
                                float* __restrict__ cc, const float* __restrict__ wihT,
                                const float* __restrict__ whhT, const float* __restrict__ bih,
                                const float* __restrict__ bhh) {
    int g = blockIdx.x;
    int j = threadIdx.x;  // 256
    __shared__ float q[128], hsh[64], gates[256];
    if (j < 128) q[j] = qstar[g * 128 + j];
    if (j < 64) hsh[j] = hh[g * 64 + j];
    __syncthreads();
    float acc = bih[j] + bhh[j];
#pragma unroll 8
    for (int k = 0; k < 128; k++) acc = fmaf(q[k], wihT[k * 256 + j], acc);
#pragma unroll 8
    for (int k = 0; k < 64; k++) acc = fmaf(hsh[k], whhT[k * 256 + j], acc);
    gates[j] = acc;
    __syncthreads();
    if (j < 64) {
        float gi = gates[j], gf = gates[64 + j], gg = gates[128 + j], go = gates[192 + j];
        float c2 = sigmoidf(gf) * cc[g * 64 + j] + sigmoidf(gi) * tanhf(gg);
        float h2 = sigmoidf(go) * tanhf(c2);
        cc[g * 64 + j] = c2;
        hh[g * 64 + j] = h2;
    }
}

// ---------------- Set2Set attention + pooling; 4 node-groups per block ----------------
__global__ void s2s_attn_kernel(const float* __restrict__ out, const float* __restrict__ hh,
                                const int* __restrict__ start, float* __restrict__ qstar) {
    int g = blockIdx.x;
    int tid = threadIdx.x;  // 256
    int d = tid & 63, sub = tid >> 6;
    int n0 = start[g], n1 = start[g + 1];
    float hd = hh[g * 64 + d];
    __shared__ float red[4][64];
    __shared__ float mxS[4], seS[4];
    float mx = -INFINITY;
    for (int n = n0 + sub; n < n1; n += 4) {
        float p = out[n * D + d] * hd;
#pragma unroll
        for (int off = 32; off; off >>= 1) p += __shfl_xor(p, off);
        mx = fmaxf(mx, p);
    }
    if (d == 0) mxS[sub] = mx;
    __syncthreads();
    mx = fmaxf(fmaxf(mxS[0], mxS[1]), fmaxf(mxS[2], mxS[3]));
    float sexp = 0.f, racc = 0.f;
    for (int n = n0 + sub; n < n1; n += 4) {
        float ond = out[n * D + d];
        float p = ond * hd;
#pragma unroll
        for (int off = 32; off; off >>= 1) p += __shfl_xor(p, off);
        float a = expf(p - mx);
        sexp += a;
        racc = fmaf(a, ond, racc);
    }
    red[sub][d] = racc;
    if (d == 0) seS[sub] = sexp;
    __syncthreads();
    if (sub == 0) {
        float rtot = red[0][d] + red[1][d] + red[2][d] + red[3][d];
        float stot = seS[0] + seS[1] + seS[2] + seS[3];
        float r = rtot / (stot + 1e-16f);
        qstar[g * 128 + d] = hd;
        qstar[g * 128 + 64 + d] = r;
    }
}

// ---------------- head ----------------
__global__ void final_kernel(const float* __restrict__ qstar, const float* __restrict__ w1,
                             const float* __restrict__ b1, const float* __restrict__ w2,
                             const float* __restrict__ b2, float* __restrict__ y) {
    int g = blockIdx.x;
    int d = threadIdx.x;  // 64
    __shared__ float q[128];
    q[d] = qstar[g * 128 + d];
    q[64 + d] = qstar[g * 128 + 64 + d];
    __syncthreads();
    float acc = b1[d];
#pragma unroll 8
    for (int k = 0; k < 128; k++) acc = fmaf(q[k], w1[d * 128 + k], acc);
    acc = fmaxf(acc, 0.f);
    float p = acc * w2[d];
#pragma unroll
    for (int off = 32; off; off >>= 1) p += __shfl_xor(p, off);
    if (d == 0) y[g] = p + b2[0];
}

extern "C" void kernel_launch(void* const* d_in, const int* in_sizes, int n_in,
                              void* d_out, int out_size, void* d_ws, size_t ws_size,
                              hipStream_t stream) {
    (void)in_sizes; (void)n_in; (void)out_size; (void)ws_size;
    const float* x = (const float*)d_in[0];
    const int* edge_index = (const int*)d_in[1];
    const float* edge_attr = (const float*)d_in[2];
    const int* batch = (const int*)d_in[3];
    const float* lin0_w = (const float*)d_in[4];
    const float* lin0_b = (const float*)d_in[5];
    const float* nn_w1 = (const float*)d_in[6];
    const float* nn_b1 = (const float*)d_in[7];
    const float* nn_w2 = (const float*)d_in[8];
    const float* nn_b2 = (const float*)d_in[9];
    const float* conv_root = (const float*)d_in[10];
    const float* conv_bias = (const float*)d_in[11];
    const float* gru_w_ih = (const float*)d_in[12];
    const float* gru_w_hh = (const float*)d_in[13];
    const float* gru_b_ih = (const float*)d_in[14];
    const float* gru_b_hh = (const float*)d_in[15];
    const float* s2s_w_ih = (const float*)d_in[16];
    const float* s2s_w_hh = (const float*)d_in[17];
    const float* s2s_b_ih = (const float*)d_in[18];
    const float* s2s_b_hh = (const float*)d_in[19];
    const float* lin1_w = (const float*)d_in[20];
    const float* lin1_b = (const float*)d_in[21];
    const float* lin2_w = (const float*)d_in[22];
    const float* lin2_b = (const float*)d_in[23];
    float* y = (float*)d_out;

    char* ws = (char*)d_ws;
    size_t off = 0;
    auto alloc = [&](size_t bytes) {
        void* p = ws + off;
        off = (off + bytes + 255) & ~(size_t)255;
        return p;
    };
    float* h = (float*)alloc((size_t)NN * D * 4);
    float* agg = (float*)alloc((size_t)NN * D * 4);
    float* invdeg = (float*)alloc((size_t)NN * 4);
    int* start = (int*)alloc((size_t)(NG + 1) * 4);
    float* qstar = (float*)alloc((size_t)NG * 128 * 4);   // 1 MB; ALIASED as w2s during MP phase
    float* hh = (float*)alloc((size_t)NG * 64 * 4);
    float* ccv = (float*)alloc((size_t)NG * 64 * 4);
    float* gruT_ih = (float*)alloc(192 * 64 * 4);
    float* gruT_hh = (float*)alloc(192 * 64 * 4);
    float* s2sT_ih = (float*)alloc(256 * 128 * 4);
    float* s2sT_hh = (float*)alloc(256 * 64 * 4);
    // w2s (swizzled bf16 nn_w2, 1 MB) aliases qstar (1 MB): read only during MP; qstar used after.
    __hip_bfloat16* w2s = (__hip_bfloat16*)qstar;

    // prep
    hipMemsetAsync(invdeg, 0, (size_t)NN * 4, stream);
    transpose_kernel<<<(192 * 64 + 255) / 256, 256, 0, stream>>>(gru_w_ih, gruT_ih, 192, 64);
    transpose_kernel<<<(192 * 64 + 255) / 256, 256, 0, stream>>>(gru_w_hh, gruT_hh, 192, 64);
    transpose_kernel<<<(256 * 128 + 255) / 256, 256, 0, stream>>>(s2s_w_ih, s2sT_ih, 256, 128);
    transpose_kernel<<<(256 * 64 + 255) / 256, 256, 0, stream>>>(s2s_w_hh, s2sT_hh, 256, 64);
    swz_w2_kernel<<<256, 256, 0, stream>>>(nn_w2, w2s);
    lin0_kernel<<<NN / 4, 256, 0, stream>>>(x, lin0_w, lin0_b, h);
    deg_kernel<<<(NE + 255) / 256, 256, 0, stream>>>(edge_index, invdeg);
    invdeg_kernel<<<(NN + 255) / 256, 256, 0, stream>>>(invdeg);
    starts_kernel<<<(NN + 255) / 256, 256, 0, stream>>>(batch, start);

    // 3 message-passing + conv+GRU iterations
    for (int it = 0; it < 3; it++) {
        hipMemsetAsync(agg, 0, (size_t)NN * D * 4, stream);
        msg_mfma_kernel<<<(NE + EB - 1) / EB, 256, 0, stream>>>(
            h, edge_attr, nn_w1, nn_b1, w2s, nn_b2, edge_index, agg);
        conv_gru_kernel<<<NN / 16, 256, 0, stream>>>(
            h, agg, invdeg, conv_root, conv_bias, gruT_ih, gruT_hh, gru_b_ih, gru_b_hh);
    }

    // Set2Set (qstar region no longer needed as w2s)
    hipMemsetAsync(qstar, 0, (size_t)NG * 128 * 4, stream);
    hipMemsetAsync(hh, 0, (size_t)NG * 64 * 4, stream);
    hipMemsetAsync(ccv, 0, (size_t)NG * 64 * 4, stream);
    for (int t = 0; t < 3; t++) {
        s2s_lstm_kernel<<<NG, 256, 0, stream>>>(qstar, hh, ccv, s2sT_ih, s2sT_hh, s2s_b_ih, s2s_b_hh);
        s2s_attn_kernel<<<NG, 256, 0, stream>>>(h, hh, start, qstar);
    }
    final_kernel<<<NG, 64, 0, stream>>>(qstar, lin1_w, lin1_b, lin2_w, lin2_b, y);
}